// Round 4
// baseline (395.123 us; speedup 1.0000x reference)
//
#include <hip/hip_runtime.h>
#include <hip/hip_bf16.h>

// FixedPointLayer: x_{k+1} = tanh(GAMMA * A_h @ x_k + b_h). fp32 in/out.
// Round-13: L2-local exchange, hang-proofed. R12 died (container killed
// twice = spin-forever) because it bet unbounded polls on three unproven
// semantics: CU-scope plain stores reaching L2, sc1-store/sc1-load
// symmetry, and s_getreg(XCC_ID). R13 keeps the idea -- a head's 32
// blocks sharing one XCD L2 can exchange at ~200cy instead of MALL
// ~600-900cy -- but the hardware itself is the oracle:
//   * capability TRIAL: each block sc0-stores an epoch-tagged token,
//     drains, BOUNDED-polls (<=1024 iters) all 32 head tokens via sc0.
//     Visibility <=> head is L2-coherent, tested with the exact
//     primitives the step loop uses (sc0 store = SE scope, guaranteed
//     to commit in L2; sc0 load = bypass L0, read L2).
//   * verdict agreement + slow path use R11's PROVEN sc0+sc1 transport
//     (ran correct twice, 114us). Unanimous per-head verdict before the
//     loop; scopes never mixed per datum.
//   * epoch-tagged tokens/flags (g_epoch bumped by probe): stale values
//     from prior graph replays are < tgt -> extra polling (worst case:
//     trial timeout -> slow path), never a spurious barrier pass.
//   * every remaining poll has a 2^22 safety cap: a wrong answer fails
//     the test visibly instead of hanging the container.
// Numerics untouched (absmax must stay 0.00390625 bit-identical).

#define FPL_GAMMA 0.9f
#define INT8_STEPS 10           // coop int8 steps (quant-floor dominated)
#define FB_STEPS 15             // fallback keeps original count
#define COOP_H 8
#define COOP_N 2048
#define COOP_HN (COOP_H * COOP_N)
#define MAX_HN 65536
#define SWZ4(i) ((i) ^ (((i) >> 3) & 7))   // float4-index LDS swizzle for xs
#define TRIAL_BOUND 1024                   // bounded trial spin (~<100us)
#define POLL_CAP (1u << 22)                // safety valve: fail, don't hang

__device__ float g_x[2][MAX_HN];              // fp32 ping-pong iterate
__device__ int   g_is_f32;                    // 1 if inputs fp32, 0 if bf16
__device__ unsigned int g_flag[COOP_H * 32];  // per-block step flags (1 line/head)
__device__ unsigned int g_tok[COOP_H * 32];   // trial tokens (1 line/head)
__device__ unsigned int g_v[COOP_H * 32];     // trial verdicts (1 line/head)
__device__ unsigned int g_epoch;              // bumped by probe each launch

__device__ __forceinline__ float bf2f(unsigned short u) {
    union { unsigned int i; float f; } v; v.i = ((unsigned int)u) << 16; return v.f;
}

// ---- scoped exchange primitives ----
// fast (same-XCD, trial-verified): sc0 store (SE scope: writes through L0,
//   commits in the XCD L2) + sc0 load (bypass L0, served by L2).
// slow (cross-XCD): sc0+sc1 store/load -- R11's proven system-scope pair.
__device__ __forceinline__ void st_ex32(bool fast, void* p, unsigned int v) {
    if (fast) asm volatile("global_store_dword %0, %1, off sc0"
                           :: "v"(p), "v"(v) : "memory");
    else      asm volatile("global_store_dword %0, %1, off sc0 sc1"
                           :: "v"(p), "v"(v) : "memory");
}
__device__ __forceinline__ unsigned int ld_ex32(bool fast, const void* p) {
    unsigned int r;
    if (fast) asm volatile("global_load_dword %0, %1, off sc0\n\ts_waitcnt vmcnt(0)"
                           : "=v"(r) : "v"(p) : "memory");
    else      asm volatile("global_load_dword %0, %1, off sc0 sc1\n\ts_waitcnt vmcnt(0)"
                           : "=v"(r) : "v"(p) : "memory");
    return r;
}
__device__ __forceinline__ float4 ld_ex128(bool fast, const void* p) {
    float4 r;
    if (fast) asm volatile("global_load_dwordx4 %0, %1, off sc0\n\ts_waitcnt vmcnt(0)"
                           : "=v"(r) : "v"(p) : "memory");
    else      asm volatile("global_load_dwordx4 %0, %1, off sc0 sc1\n\ts_waitcnt vmcnt(0)"
                           : "=v"(r) : "v"(p) : "memory");
    return r;
}

// Input dtype probe (parallelized) + token/flag/verdict reset + epoch bump.
// Kernel-boundary release makes these visible to the coop kernel.
__global__ __launch_bounds__(256) void fpl_probe(const unsigned short* __restrict__ A) {
    const int t = threadIdx.x;
    g_flag[t] = 0u;
    g_tok[t]  = 0u;
    g_v[t]    = 0u;
    if (t == 0) g_epoch = g_epoch + 1u;
    if (t < 64) {
        int bad = 0;
#pragma unroll
        for (int k = 0; k < 4; ++k) {
            const float av = fabsf(bf2f(A[(t << 2) + k]));
            if (!(av <= 1e3f)) bad = 1;
        }
        const unsigned long long any = __ballot(bad);
        if (t == 0) g_is_f32 = (any != 0ull) ? 1 : 0;
    }
}

// x1 = tanh(b) into g_x[0] -- FALLBACK path only (coop computes x1 locally).
__global__ __launch_bounds__(256) void fpl_init(const void* __restrict__ bv, int hn) {
    int i = blockIdx.x * 256 + threadIdx.x;
    if (i < hn) {
        float bval = g_is_f32 ? ((const float*)bv)[i]
                              : bf2f(((const unsigned short*)bv)[i]);
        g_x[0][i] = tanhf(bval);
    }
}

// Decode 4 int8 lanes of w against float4 x into acc.
__device__ __forceinline__ float dec4(unsigned int w, const float4 x, float acc) {
    acc = fmaf((float)((int)(w << 24) >> 24), x.x, acc);
    acc = fmaf((float)((int)(w << 16) >> 24), x.y, acc);
    acc = fmaf((float)((int)(w <<  8) >> 24), x.z, acc);
    acc = fmaf((float)((int)w >> 24),         x.w, acc);
    return acc;
}

// Quantize one row (held in v4[8], this wave's 2048 cols) into LDS int8.
__device__ __forceinline__ void quant_row(const float4* v4, int lrow, int lane,
                                          unsigned int* aq, float* rowscale) {
    float m = 0.f;
#pragma unroll
    for (int k = 0; k < 8; ++k)
        m = fmaxf(m, fmaxf(fmaxf(fabsf(v4[k].x), fabsf(v4[k].y)),
                           fmaxf(fabsf(v4[k].z), fabsf(v4[k].w))));
#pragma unroll
    for (int off = 32; off > 0; off >>= 1)
        m = fmaxf(m, __shfl_xor(m, off, 64));
    m = fmaxf(m, 1e-30f);
    const float inv = 127.0f / m;
    if (lane == 0) rowscale[lrow] = m * (1.0f / 127.0f);
    unsigned int* aqr = aq + lrow * 512;
#pragma unroll
    for (int k = 0; k < 8; ++k) {
        const int q0 = (int)rintf(v4[k].x * inv);
        const int q1 = (int)rintf(v4[k].y * inv);
        const int q2 = (int)rintf(v4[k].z * inv);
        const int q3 = (int)rintf(v4[k].w * inv);
        aqr[(k << 6) + lane] = (unsigned int)(q0 & 255)
                             | ((unsigned int)(q1 & 255) << 8)
                             | ((unsigned int)(q2 & 255) << 16)
                             | ((unsigned int)(q3 & 255) << 24);
    }
}

// ---------------- persistent cooperative solver ----------------
// Grid 256 x 512 (1 block/CU by LDS). head = bid&7: with round-robin
// dispatch all 32 blocks of a head share one XCD -- verified empirically
// by the trial below, never assumed.
__global__ __launch_bounds__(512)
void fpl_coop(const void* __restrict__ Av,
              const void* __restrict__ bv,
              float* __restrict__ out) {
    __shared__ unsigned int aq[64 * 512];   // 64 rows x 2048 int8 = 128 KiB
    __shared__ float xs[COOP_N];            // 8 KiB: head's x (SWZ4 layout)
    __shared__ float red[64 * 65];          // 16.6 KiB: partials, padded
    __shared__ float rowscale[64];          // 256 B

    const int tid  = threadIdx.x;
    const int wave = tid >> 6;
    const int lane = tid & 63;
    const int bid  = blockIdx.x;             // 0..255
    const int head = bid & 7;                // XCD affinity (trial-checked)
    const int jblk = bid >> 3;               // block index within head, 0..31
    const int rowBase = jblk << 6;           // 64 rows/block
    const bool isf32 = (g_is_f32 != 0);      // wave-uniform
    const int lrow0 = wave << 3;             // wave's first local row

    // ---- prologue: quantize my wave's 8 rows into LDS int8 ----
    if (isf32) {
        // 2-deep pipelined: issue row r+1 loads before quantizing row r.
        const float* Ab = (const float*)Av;
        const size_t grow0 = (size_t)(head * COOP_N + rowBase + lrow0);
        float4 cur[8], nxt[8];
        {
            const float* Ar = Ab + (grow0 << 11);
#pragma unroll
            for (int k = 0; k < 8; ++k)
                cur[k] = *(const float4*)(Ar + ((k << 8) + (lane << 2)));
        }
#pragma unroll 1
        for (int r = 0; r < 8; ++r) {
            if (r < 7) {
                const float* Ar = Ab + ((grow0 + r + 1) << 11);
#pragma unroll
                for (int k = 0; k < 8; ++k)
                    nxt[k] = *(const float4*)(Ar + ((k << 8) + (lane << 2)));
            }
            quant_row(cur, lrow0 + r, lane, aq, rowscale);
#pragma unroll
            for (int k = 0; k < 8; ++k) cur[k] = nxt[k];
        }
    } else {
#pragma unroll 1
        for (int r = 0; r < 8; ++r) {
            const int lrow = lrow0 + r;
            const size_t grow = (size_t)(head * COOP_N + rowBase + lrow);
            const unsigned short* Ar = (const unsigned short*)Av + (grow << 11);
            float4 v4[8];
#pragma unroll
            for (int k = 0; k < 8; ++k) {
                const ushort4 t = *(const ushort4*)(Ar + ((k << 8) + (lane << 2)));
                v4[k] = make_float4(bf2f(t.x), bf2f(t.y), bf2f(t.z), bf2f(t.w));
            }
            quant_row(v4, lrow, lane, aq, rowscale);
        }
    }

    // ---- local x1 = tanh(b): every block computes the head's full x1 ----
    {
        float4 bb;
        if (isf32) bb = ((const float4*)bv)[(head << 9) + tid];
        else {
            const ushort4 t = ((const ushort4*)bv)[(head << 9) + tid];
            bb = make_float4(bf2f(t.x), bf2f(t.y), bf2f(t.z), bf2f(t.w));
        }
        ((float4*)xs)[SWZ4(tid)] =
            make_float4(tanhf(bb.x), tanhf(bb.y), tanhf(bb.z), tanhf(bb.w));
    }

    // Writer threads (tid%8==0) own local row rl=tid>>3; preload b.
    const int rl   = tid >> 3;               // 0..63
    const int gRow = head * COOP_N + rowBase + rl;
    float breg = 0.f;
    if ((tid & 7) == 0)
        breg = isf32 ? ((const float*)bv)[gRow]
                     : bf2f(((const unsigned short*)bv)[gRow]);

    // epoch: read over proven transport; wave-uniform
    const unsigned int epoch = ld_ex32(false, &g_epoch);

    // ---- capability trial: can head peers exchange via sc0 (XCD L2)? ----
    bool fast;
    {
        if (tid == 0) st_ex32(true, &g_tok[(head << 5) + jblk], epoch);
        asm volatile("s_waitcnt vmcnt(0)" ::: "memory");
        // bounded poll of all 32 head tokens with the FAST primitives
        bool ok = false;
        const unsigned int* tp = &g_tok[(head << 5) + (lane & 31)];
        for (int it = 0; it < TRIAL_BOUND; ++it) {
            const unsigned int v = ld_ex32(true, tp);
            if (__all((int)(v == epoch))) { ok = true; break; }
            __builtin_amdgcn_s_sleep(1);
        }
        // unanimous agreement over PROVEN system-scope transport
        if (tid == 0)
            st_ex32(false, &g_v[(head << 5) + jblk],
                    (epoch << 1) | (ok ? 1u : 0u));
        asm volatile("s_waitcnt vmcnt(0)" ::: "memory");
        const unsigned int* vp = &g_v[(head << 5) + (lane & 31)];
        unsigned int w = 0u;
        for (unsigned int it = 0; it < POLL_CAP; ++it) {
            w = ld_ex32(false, vp);
            if (__all((int)((w >> 1) == epoch))) break;
            __builtin_amdgcn_s_sleep(1);
        }
        fast = __all((int)(w == ((epoch << 1) | 1u)));
    }

    __syncthreads();                          // aq + rowscale + xs visible
    const float sreg = rowscale[rl];          // writer's row scale
    const float4* xsf4 = (const float4*)xs;
    const unsigned int ftag = epoch << 4;     // per-launch flag namespace

    // ---- int8 fixed-point steps ----
    for (int s = 0; s < INT8_STEPS; ++s) {
        float acc[8];
#pragma unroll
        for (int r = 0; r < 8; ++r) acc[r] = 0.f;
#pragma unroll
        for (int j = 0; j < 2; ++j) {
            const int base = (j << 8) + (lane << 2);     // f4 idx == u32 idx
            const float4 x0 = xsf4[SWZ4(base + 0)];
            const float4 x1 = xsf4[SWZ4(base + 1)];
            const float4 x2 = xsf4[SWZ4(base + 2)];
            const float4 x3 = xsf4[SWZ4(base + 3)];
#pragma unroll
            for (int r = 0; r < 8; ++r) {
                const uint4 w = *(const uint4*)(aq + (lrow0 + r) * 512 + base);
                float a = acc[r];
                a = dec4(w.x, x0, a);
                a = dec4(w.y, x1, a);
                a = dec4(w.z, x2, a);
                a = dec4(w.w, x3, a);
                acc[r] = a;
            }
        }

        // transpose partials via LDS (stride 65 -> conflict-free)
#pragma unroll
        for (int r = 0; r < 8; ++r)
            red[(lrow0 + r) * 65 + lane] = acc[r];
        __syncthreads();                                  // (1)

        // thread t: row rl=t>>3, chunk c=t&7: serial-8 + 3-level butterfly
        const int c = tid & 7;
        const float* rr = &red[rl * 65 + (c << 3)];
        float v = ((rr[0] + rr[1]) + (rr[2] + rr[3]))
                + ((rr[4] + rr[5]) + (rr[6] + rr[7]));
        v += __shfl_xor(v, 1, 64);
        v += __shfl_xor(v, 2, 64);
        v += __shfl_xor(v, 4, 64);

        // coalesced exchange store: 8 lanes/wave (rows 8w..8w+7, consecutive)
        if (c == 0)
            st_ex32(fast, &g_x[s & 1][gRow],
                    __float_as_uint(tanhf(FPL_GAMMA * sreg * v + breg)));
        // drain MY stores before the block-wide barrier (inline-asm stores
        // are invisible to the compiler's waitcnt bookkeeping)
        asm volatile("s_waitcnt vmcnt(0)" ::: "memory");

        __syncthreads();                                  // (2) all stores acked
        // all 64 x-stores of this block committed at the chosen scope:
        // publish the epoch-tagged flag at the same scope
        if (tid == 0)
            st_ex32(fast, &g_flag[(head << 5) + jblk],
                    ftag + (unsigned int)(s + 1));

        // every wave polls ALL 32 flags of its head; exits when the whole
        // head has published step s+1 of THIS launch (stale epochs are <).
        {
            const unsigned int tgt = ftag + (unsigned int)(s + 1);
            const unsigned int* fp = &g_flag[(head << 5) + (tid & 31)];
            for (unsigned int it = 0; it < POLL_CAP; ++it) {
                const unsigned int f = ld_ex32(fast, fp);
                if (__all((int)(f >= tgt))) break;
                __builtin_amdgcn_s_sleep(1);
            }
        }

        // reload head's x at the matching scope, swizzled into LDS
        {
            const float4 xv = ld_ex128(fast,
                                       (const float4*)&g_x[s & 1][head << 11] + tid);
            ((float4*)xs)[SWZ4(tid)] = xv;
        }
        __syncthreads();                                  // (3)
    }

    // ---- final differentiable step with EXACT A (streamed, L3-resident) ----
#pragma unroll 1
    for (int r = 0; r < 8; ++r) {
        const int lrow = lrow0 + r;
        const size_t grow = (size_t)(head * COOP_N + rowBase + lrow);
        float acc = 0.f;
        if (isf32) {
            const float* Ar = (const float*)Av + (grow << 11);
#pragma unroll
            for (int k = 0; k < 8; ++k) {
                const float4 a = *(const float4*)(Ar + ((k << 8) + (lane << 2)));
                const float4 x = xsf4[SWZ4((k << 6) + lane)];
                acc += a.x * x.x + a.y * x.y + a.z * x.z + a.w * x.w;
            }
        } else {
            const unsigned short* Ar = (const unsigned short*)Av + (grow << 11);
#pragma unroll
            for (int k = 0; k < 8; ++k) {
                const ushort4 t = *(const ushort4*)(Ar + ((k << 8) + (lane << 2)));
                const float4 x = xsf4[SWZ4((k << 6) + lane)];
                acc += bf2f(t.x) * x.x + bf2f(t.y) * x.y
                     + bf2f(t.z) * x.z + bf2f(t.w) * x.w;
            }
        }
#pragma unroll
        for (int off = 32; off > 0; off >>= 1)
            acc += __shfl_xor(acc, off, 64);
        if (lane == 0) {
            const float bval = isf32 ? ((const float*)bv)[grow]
                                     : bf2f(((const unsigned short*)bv)[grow]);
            out[grow] = tanhf(FPL_GAMMA * acc + bval);
        }
    }
}

// ---------------- generic fallback (round-3 structure) ----------------
template <bool FINAL>
__global__ __launch_bounds__(256) void fpl_step_raw(const void* __restrict__ Av,
                                                    const void* __restrict__ bv,
                                                    int src, int N,
                                                    float* __restrict__ out) {
    extern __shared__ float xsd[];
    const int rowBlocks = N >> 4;
    const int head = blockIdx.x / rowBlocks;
    const int r0   = (blockIdx.x % rowBlocks) << 4;
    const int tid  = threadIdx.x;
    const float4* xg = (const float4*)(g_x[src] + head * N);
    for (int j = tid; j < (N >> 2); j += 256) ((float4*)xsd)[j] = xg[j];
    __syncthreads();
    const int wave = tid >> 6, lane = tid & 63;
    const int row = r0 + (wave << 2);
    float acc0 = 0.f, acc1 = 0.f, acc2 = 0.f, acc3 = 0.f;
    const bool isf32 = (g_is_f32 != 0);
    if (isf32) {
        const float* A0 = (const float*)Av + (size_t)(head * N + row) * N;
        for (int cb = 0; cb < N; cb += 256) {
            const int c = cb + (lane << 2);
            const float4 xv = *(const float4*)(xsd + c);
            const float4 a0 = *(const float4*)(A0 + c);
            const float4 a1 = *(const float4*)(A0 + N + c);
            const float4 a2 = *(const float4*)(A0 + 2 * N + c);
            const float4 a3 = *(const float4*)(A0 + 3 * N + c);
            acc0 += a0.x*xv.x + a0.y*xv.y + a0.z*xv.z + a0.w*xv.w;
            acc1 += a1.x*xv.x + a1.y*xv.y + a1.z*xv.z + a1.w*xv.w;
            acc2 += a2.x*xv.x + a2.y*xv.y + a2.z*xv.z + a2.w*xv.w;
            acc3 += a3.x*xv.x + a3.y*xv.y + a3.z*xv.z + a3.w*xv.w;
        }
    } else {
        const unsigned short* A0 = (const unsigned short*)Av + (size_t)(head * N + row) * N;
        for (int cb = 0; cb < N; cb += 256) {
            const int c = cb + (lane << 2);
            const float4 xv = *(const float4*)(xsd + c);
            const ushort4 a0 = *(const ushort4*)(A0 + c);
            const ushort4 a1 = *(const ushort4*)(A0 + N + c);
            const ushort4 a2 = *(const ushort4*)(A0 + 2 * N + c);
            const ushort4 a3 = *(const ushort4*)(A0 + 3 * N + c);
            acc0 += bf2f(a0.x)*xv.x + bf2f(a0.y)*xv.y + bf2f(a0.z)*xv.z + bf2f(a0.w)*xv.w;
            acc1 += bf2f(a1.x)*xv.x + bf2f(a1.y)*xv.y + bf2f(a1.z)*xv.z + bf2f(a1.w)*xv.w;
            acc2 += bf2f(a2.x)*xv.x + bf2f(a2.y)*xv.y + bf2f(a2.z)*xv.z + bf2f(a2.w)*xv.w;
            acc3 += bf2f(a3.x)*xv.x + bf2f(a3.y)*xv.y + bf2f(a3.z)*xv.z + bf2f(a3.w)*xv.w;
        }
    }
#pragma unroll
    for (int off = 32; off > 0; off >>= 1) {
        acc0 += __shfl_xor(acc0, off, 64);
        acc1 += __shfl_xor(acc1, off, 64);
        acc2 += __shfl_xor(acc2, off, 64);
        acc3 += __shfl_xor(acc3, off, 64);
    }
    if (lane < 4) {
        float acc = (lane == 0) ? acc0 : (lane == 1) ? acc1 : (lane == 2) ? acc2 : acc3;
        const int idx = head * N + row + lane;
        const float bval = isf32 ? ((const float*)bv)[idx]
                                 : bf2f(((const unsigned short*)bv)[idx]);
        const float y = tanhf(FPL_GAMMA * acc + bval);
        if (FINAL) out[idx] = y;
        else       g_x[1 - src][idx] = y;
    }
}

extern "C" void kernel_launch(void* const* d_in, const int* in_sizes, int n_in,
                              void* d_out, int out_size, void* d_ws, size_t ws_size,
                              hipStream_t stream) {
    (void)d_ws; (void)ws_size; (void)n_in; (void)out_size;
    const void* A = d_in[0];
    const void* b = d_in[1];
    long szA = in_sizes[0], szb = in_sizes[1];
    if (szA < szb) { const void* t = A; A = b; b = t; long s = szA; szA = szb; szb = s; }
    const int HN = (int)szb;
    const int N  = (int)(szA / szb);
    float* out = (float*)d_out;

    // probe zeroes tokens/flags/verdicts + bumps epoch (graph-replay safe)
    fpl_probe<<<dim3(1), dim3(256), 0, stream>>>((const unsigned short*)A);

    bool done = false;
    if (N == COOP_N && HN == COOP_HN) {
        void* args[] = { (void*)&A, (void*)&b, (void*)&out };
        hipError_t rc = hipLaunchCooperativeKernel((const void*)fpl_coop,
                                                   dim3(256), dim3(512),
                                                   args, 0, stream);
        done = (rc == hipSuccess);
    }
    if (!done) {
        fpl_init<<<dim3((HN + 255) / 256), dim3(256), 0, stream>>>(b, HN);
        const int grid = HN >> 4;
        const size_t lds = (size_t)N * sizeof(float);
        int src = 0;
        for (int s = 0; s < FB_STEPS; ++s) {
            fpl_step_raw<false><<<dim3(grid), dim3(256), lds, stream>>>(A, b, src, N, nullptr);
            src ^= 1;
        }
        fpl_step_raw<true><<<dim3(grid), dim3(256), lds, stream>>>(A, b, src, N, out);
    }
}

// Round 5
// 295.949 us; speedup vs baseline: 1.3351x; 1.3351x over previous
//
#include <hip/hip_runtime.h>
#include <hip/hip_bf16.h>

// FixedPointLayer: x_{k+1} = tanh(GAMMA * A_h @ x_k + b_h). fp32 in/out.
// Round-14: ASYNC (chaotic) Jacobi -- stop paying for synchrony.
// R12/R13 proved the L2-local-exchange idea doesn't pay (trial timed out:
// either coop placement isn't bid%8 round-robin or sc0 isn't cross-CU
// visible); abandoned. R11's per-step 7.5us decomposes as compute 1.7 +
// reduce 0.4 + store 0.7 + FULL-SYNC WAIT 2.5-3 + reload 0.7 + barriers.
// The iteration is a contraction (rho ~ 0.36): asynchronous Jacobi with
// staleness <= 1 converges at sqrt(rho) = 0.6/step worst-case, 0.36
// typical. So: single in-place x buffer; block publishes chunk then flag;
// iteration i only requires peers >= i-1 (fast-path check >= i passes
// instantly in lockstep; reload issued SPECULATIVELY concurrent with the
// check -- flag-after-drain bounds the race to d=1). One true barrier
// remains: final poll >= S+1 before the exact-A step. Steps 10 -> 13 as
// staleness insurance: worst-case residual 0.6^13*0.7 ~ 9e-4 << 2e-3
// quant floor; typical ~1e-5. All transport on R11's PROVEN sc0+sc1
// primitives; every poll capped (fail visibly, never hang).
// Numerics floor untouched (absmax stays 0.00390625).

#define FPL_GAMMA 0.9f
#define INT8_STEPS 13           // async steps (staleness-1 insurance margin)
#define FB_STEPS 15             // fallback keeps original count
#define COOP_H 8
#define COOP_N 2048
#define COOP_HN (COOP_H * COOP_N)
#define MAX_HN 65536
#define SWZ4(i) ((i) ^ (((i) >> 3) & 7))   // float4-index LDS swizzle for xs
#define POLL_CAP (1u << 22)                // safety valve: fail, don't hang

__device__ float g_x[2][MAX_HN];              // [0]: coop in-place iterate; fallback ping-pongs
__device__ int   g_is_f32;                    // 1 if inputs fp32, 0 if bf16
__device__ unsigned int g_flag[COOP_H * 32];  // per-block published level

__device__ __forceinline__ float bf2f(unsigned short u) {
    union { unsigned int i; float f; } v; v.i = ((unsigned int)u) << 16; return v.f;
}

// ---- proven system-scope transport (R11: correct twice at 114us) ----
// sc0 sc1: bypass L0 + XCD-L2 both ways; stores commit at the coherence
// point, vmcnt ack = commit; loads read the coherence point.
__device__ __forceinline__ void st_cp32(void* p, unsigned int v) {
    asm volatile("global_store_dword %0, %1, off sc0 sc1"
                 :: "v"(p), "v"(v) : "memory");
}
__device__ __forceinline__ unsigned int ld_cp32(const void* p) {
    unsigned int r;
    asm volatile("global_load_dword %0, %1, off sc0 sc1\n\ts_waitcnt vmcnt(0)"
                 : "=v"(r) : "v"(p) : "memory");
    return r;
}
__device__ __forceinline__ float4 ld_cp128(const void* p) {
    float4 r;
    asm volatile("global_load_dwordx4 %0, %1, off sc0 sc1\n\ts_waitcnt vmcnt(0)"
                 : "=v"(r) : "v"(p) : "memory");
    return r;
}

// Input dtype probe (parallelized) + flag zeroing (graph-replay safe;
// kernel-boundary ordering makes these visible to the coop kernel).
__global__ __launch_bounds__(256) void fpl_probe(const unsigned short* __restrict__ A) {
    const int t = threadIdx.x;
    g_flag[t] = 0u;
    if (t < 64) {
        int bad = 0;
#pragma unroll
        for (int k = 0; k < 4; ++k) {
            const float av = fabsf(bf2f(A[(t << 2) + k]));
            if (!(av <= 1e3f)) bad = 1;
        }
        const unsigned long long any = __ballot(bad);
        if (t == 0) g_is_f32 = (any != 0ull) ? 1 : 0;
    }
}

// x1 = tanh(b) into g_x[0] -- FALLBACK path only (coop computes x1 locally).
__global__ __launch_bounds__(256) void fpl_init(const void* __restrict__ bv, int hn) {
    int i = blockIdx.x * 256 + threadIdx.x;
    if (i < hn) {
        float bval = g_is_f32 ? ((const float*)bv)[i]
                              : bf2f(((const unsigned short*)bv)[i]);
        g_x[0][i] = tanhf(bval);
    }
}

// Decode 4 int8 lanes of w against float4 x into acc.
__device__ __forceinline__ float dec4(unsigned int w, const float4 x, float acc) {
    acc = fmaf((float)((int)(w << 24) >> 24), x.x, acc);
    acc = fmaf((float)((int)(w << 16) >> 24), x.y, acc);
    acc = fmaf((float)((int)(w <<  8) >> 24), x.z, acc);
    acc = fmaf((float)((int)w >> 24),         x.w, acc);
    return acc;
}

// Quantize one row (held in v4[8], this wave's 2048 cols) into LDS int8.
__device__ __forceinline__ void quant_row(const float4* v4, int lrow, int lane,
                                          unsigned int* aq, float* rowscale) {
    float m = 0.f;
#pragma unroll
    for (int k = 0; k < 8; ++k)
        m = fmaxf(m, fmaxf(fmaxf(fabsf(v4[k].x), fabsf(v4[k].y)),
                           fmaxf(fabsf(v4[k].z), fabsf(v4[k].w))));
#pragma unroll
    for (int off = 32; off > 0; off >>= 1)
        m = fmaxf(m, __shfl_xor(m, off, 64));
    m = fmaxf(m, 1e-30f);
    const float inv = 127.0f / m;
    if (lane == 0) rowscale[lrow] = m * (1.0f / 127.0f);
    unsigned int* aqr = aq + lrow * 512;
#pragma unroll
    for (int k = 0; k < 8; ++k) {
        const int q0 = (int)rintf(v4[k].x * inv);
        const int q1 = (int)rintf(v4[k].y * inv);
        const int q2 = (int)rintf(v4[k].z * inv);
        const int q3 = (int)rintf(v4[k].w * inv);
        aqr[(k << 6) + lane] = (unsigned int)(q0 & 255)
                             | ((unsigned int)(q1 & 255) << 8)
                             | ((unsigned int)(q2 & 255) << 16)
                             | ((unsigned int)(q3 & 255) << 24);
    }
}

// ---------------- persistent cooperative solver ----------------
// Grid 256 x 512 (1 block/CU by LDS). 32 blocks/head, 64 rows/block.
__global__ __launch_bounds__(512)
void fpl_coop(const void* __restrict__ Av,
              const void* __restrict__ bv,
              float* __restrict__ out) {
    __shared__ unsigned int aq[64 * 512];   // 64 rows x 2048 int8 = 128 KiB
    __shared__ float xs[COOP_N];            // 8 KiB: head's x (SWZ4 layout)
    __shared__ float red[64 * 65];          // 16.6 KiB: partials, padded
    __shared__ float rowscale[64];          // 256 B

    const int tid  = threadIdx.x;
    const int wave = tid >> 6;
    const int lane = tid & 63;
    const int bid  = blockIdx.x;             // 0..255
    const int head = bid & 7;
    const int jblk = bid >> 3;               // block index within head, 0..31
    const int rowBase = jblk << 6;           // 64 rows/block
    const bool isf32 = (g_is_f32 != 0);      // wave-uniform
    const int lrow0 = wave << 3;             // wave's first local row

    // ---- prologue: quantize my wave's 8 rows into LDS int8 ----
    if (isf32) {
        // 2-deep pipelined: issue row r+1 loads before quantizing row r.
        const float* Ab = (const float*)Av;
        const size_t grow0 = (size_t)(head * COOP_N + rowBase + lrow0);
        float4 cur[8], nxt[8];
        {
            const float* Ar = Ab + (grow0 << 11);
#pragma unroll
            for (int k = 0; k < 8; ++k)
                cur[k] = *(const float4*)(Ar + ((k << 8) + (lane << 2)));
        }
#pragma unroll 1
        for (int r = 0; r < 8; ++r) {
            if (r < 7) {
                const float* Ar = Ab + ((grow0 + r + 1) << 11);
#pragma unroll
                for (int k = 0; k < 8; ++k)
                    nxt[k] = *(const float4*)(Ar + ((k << 8) + (lane << 2)));
            }
            quant_row(cur, lrow0 + r, lane, aq, rowscale);
#pragma unroll
            for (int k = 0; k < 8; ++k) cur[k] = nxt[k];
        }
    } else {
#pragma unroll 1
        for (int r = 0; r < 8; ++r) {
            const int lrow = lrow0 + r;
            const size_t grow = (size_t)(head * COOP_N + rowBase + lrow);
            const unsigned short* Ar = (const unsigned short*)Av + (grow << 11);
            float4 v4[8];
#pragma unroll
            for (int k = 0; k < 8; ++k) {
                const ushort4 t = *(const ushort4*)(Ar + ((k << 8) + (lane << 2)));
                v4[k] = make_float4(bf2f(t.x), bf2f(t.y), bf2f(t.z), bf2f(t.w));
            }
            quant_row(v4, lrow, lane, aq, rowscale);
        }
    }

    // ---- local x1 = tanh(b): every block fills the head's FULL x1 in LDS
    // (level-1 everywhere locally; no exchange needed for iteration 1) ----
    {
        float4 bb;
        if (isf32) bb = ((const float4*)bv)[(head << 9) + tid];
        else {
            const ushort4 t = ((const ushort4*)bv)[(head << 9) + tid];
            bb = make_float4(bf2f(t.x), bf2f(t.y), bf2f(t.z), bf2f(t.w));
        }
        ((float4*)xs)[SWZ4(tid)] =
            make_float4(tanhf(bb.x), tanhf(bb.y), tanhf(bb.z), tanhf(bb.w));
    }

    // Writer threads (tid%8==0) own local row rl=tid>>3; preload b.
    const int rl   = tid >> 3;               // 0..63
    const int gRow = head * COOP_N + rowBase + rl;
    float breg = 0.f;
    if ((tid & 7) == 0)
        breg = isf32 ? ((const float*)bv)[gRow]
                     : bf2f(((const unsigned short*)bv)[gRow]);

    // publish my level-1 chunk (identical bits to the LDS x1: same tanhf(b))
    if ((tid & 7) == 0)
        st_cp32(&g_x[0][gRow], __float_as_uint(tanhf(breg)));
    asm volatile("s_waitcnt vmcnt(0)" ::: "memory");

    __syncthreads();                          // aq + rowscale + xs visible
    const float sreg = rowscale[rl];          // writer's row scale
    const float4* xsf4 = (const float4*)xs;
    const int c = tid & 7;                    // writer iff c==0

    if (tid == 0) st_cp32(&g_flag[(head << 5) + jblk], 1u);

    unsigned int* const fbase = &g_flag[(head << 5)];
    const float4* const gx4   = (const float4*)&g_x[0][head << 11];

    // ---- async int8 fixed-point iterations (levels 2..S+1) ----
    for (int i = 1; i <= INT8_STEPS; ++i) {
        if (i >= 2) {
            // speculative reload concurrent with the fast-path flag check.
            // fast path (lockstep): peers >= i observed -> race bounds the
            // reload to components >= i-1 (d<=1). straggler path: bounded
            // poll for >= i-1, then re-read (issued after poll completes ->
            // sees everything committed before the flag, still d<=1).
            float4 xv = ld_cp128(gx4 + tid);
            unsigned int f = ld_cp32(fbase + (tid & 31));
            if (!__all((int)(f >= (unsigned int)i))) {
                const unsigned int tgt = (unsigned int)(i - 1);
                for (unsigned int it = 0; it < POLL_CAP; ++it) {
                    f = ld_cp32(fbase + (tid & 31));
                    if (__all((int)(f >= tgt))) break;
                    __builtin_amdgcn_s_sleep(1);
                }
                xv = ld_cp128(gx4 + tid);
            }
            ((float4*)xs)[SWZ4(tid)] = xv;
            __syncthreads();
        }

        float acc[8];
#pragma unroll
        for (int r = 0; r < 8; ++r) acc[r] = 0.f;
#pragma unroll
        for (int j = 0; j < 2; ++j) {
            const int base = (j << 8) + (lane << 2);     // f4 idx == u32 idx
            const float4 x0 = xsf4[SWZ4(base + 0)];
            const float4 x1 = xsf4[SWZ4(base + 1)];
            const float4 x2 = xsf4[SWZ4(base + 2)];
            const float4 x3 = xsf4[SWZ4(base + 3)];
#pragma unroll
            for (int r = 0; r < 8; ++r) {
                const uint4 w = *(const uint4*)(aq + (lrow0 + r) * 512 + base);
                float a = acc[r];
                a = dec4(w.x, x0, a);
                a = dec4(w.y, x1, a);
                a = dec4(w.z, x2, a);
                a = dec4(w.w, x3, a);
                acc[r] = a;
            }
        }

        // transpose partials via LDS (stride 65 -> conflict-free)
#pragma unroll
        for (int r = 0; r < 8; ++r)
            red[(lrow0 + r) * 65 + lane] = acc[r];
        __syncthreads();

        // thread t: row rl=t>>3, chunk c=t&7: serial-8 + 3-level butterfly
        const float* rr = &red[rl * 65 + (c << 3)];
        float v = ((rr[0] + rr[1]) + (rr[2] + rr[3]))
                + ((rr[4] + rr[5]) + (rr[6] + rr[7]));
        v += __shfl_xor(v, 1, 64);
        v += __shfl_xor(v, 2, 64);
        v += __shfl_xor(v, 4, 64);

        // publish level i+1 chunk in place (8 coalesced lanes/wave)
        if (c == 0)
            st_cp32(&g_x[0][gRow],
                    __float_as_uint(tanhf(FPL_GAMMA * sreg * v + breg)));
        asm volatile("s_waitcnt vmcnt(0)" ::: "memory");
        __syncthreads();                      // all 64 chunk stores committed
        if (tid == 0)
            st_cp32(fbase + jblk, (unsigned int)(i + 1));
        // fire-and-forget: next iteration's poll (or the final barrier)
        // provides the pacing; max peer lead is 1 by construction.
    }

    // ---- the one true barrier: everyone at level S+1, then exact step ----
    {
        const unsigned int tgt = (unsigned int)(INT8_STEPS + 1);
        for (unsigned int it = 0; it < POLL_CAP; ++it) {
            const unsigned int f = ld_cp32(fbase + (tid & 31));
            if (__all((int)(f >= tgt))) break;
            __builtin_amdgcn_s_sleep(1);
        }
        const float4 xv = ld_cp128(gx4 + tid);
        ((float4*)xs)[SWZ4(tid)] = xv;
        __syncthreads();
    }

    // ---- final differentiable step with EXACT A (streamed, L3-resident) ----
#pragma unroll 1
    for (int r = 0; r < 8; ++r) {
        const int lrow = lrow0 + r;
        const size_t grow = (size_t)(head * COOP_N + rowBase + lrow);
        float acc = 0.f;
        if (isf32) {
            const float* Ar = (const float*)Av + (grow << 11);
#pragma unroll
            for (int k = 0; k < 8; ++k) {
                const float4 a = *(const float4*)(Ar + ((k << 8) + (lane << 2)));
                const float4 x = xsf4[SWZ4((k << 6) + lane)];
                acc += a.x * x.x + a.y * x.y + a.z * x.z + a.w * x.w;
            }
        } else {
            const unsigned short* Ar = (const unsigned short*)Av + (grow << 11);
#pragma unroll
            for (int k = 0; k < 8; ++k) {
                const ushort4 t = *(const ushort4*)(Ar + ((k << 8) + (lane << 2)));
                const float4 x = xsf4[SWZ4((k << 6) + lane)];
                acc += bf2f(t.x) * x.x + bf2f(t.y) * x.y
                     + bf2f(t.z) * x.z + bf2f(t.w) * x.w;
            }
        }
#pragma unroll
        for (int off = 32; off > 0; off >>= 1)
            acc += __shfl_xor(acc, off, 64);
        if (lane == 0) {
            const float bval = isf32 ? ((const float*)bv)[grow]
                                     : bf2f(((const unsigned short*)bv)[grow]);
            out[grow] = tanhf(FPL_GAMMA * acc + bval);
        }
    }
}

// ---------------- generic fallback (round-3 structure) ----------------
template <bool FINAL>
__global__ __launch_bounds__(256) void fpl_step_raw(const void* __restrict__ Av,
                                                    const void* __restrict__ bv,
                                                    int src, int N,
                                                    float* __restrict__ out) {
    extern __shared__ float xsd[];
    const int rowBlocks = N >> 4;
    const int head = blockIdx.x / rowBlocks;
    const int r0   = (blockIdx.x % rowBlocks) << 4;
    const int tid  = threadIdx.x;
    const float4* xg = (const float4*)(g_x[src] + head * N);
    for (int j = tid; j < (N >> 2); j += 256) ((float4*)xsd)[j] = xg[j];
    __syncthreads();
    const int wave = tid >> 6, lane = tid & 63;
    const int row = r0 + (wave << 2);
    float acc0 = 0.f, acc1 = 0.f, acc2 = 0.f, acc3 = 0.f;
    const bool isf32 = (g_is_f32 != 0);
    if (isf32) {
        const float* A0 = (const float*)Av + (size_t)(head * N + row) * N;
        for (int cb = 0; cb < N; cb += 256) {
            const int c = cb + (lane << 2);
            const float4 xv = *(const float4*)(xsd + c);
            const float4 a0 = *(const float4*)(A0 + c);
            const float4 a1 = *(const float4*)(A0 + N + c);
            const float4 a2 = *(const float4*)(A0 + 2 * N + c);
            const float4 a3 = *(const float4*)(A0 + 3 * N + c);
            acc0 += a0.x*xv.x + a0.y*xv.y + a0.z*xv.z + a0.w*xv.w;
            acc1 += a1.x*xv.x + a1.y*xv.y + a1.z*xv.z + a1.w*xv.w;
            acc2 += a2.x*xv.x + a2.y*xv.y + a2.z*xv.z + a2.w*xv.w;
            acc3 += a3.x*xv.x + a3.y*xv.y + a3.z*xv.z + a3.w*xv.w;
        }
    } else {
        const unsigned short* A0 = (const unsigned short*)Av + (size_t)(head * N + row) * N;
        for (int cb = 0; cb < N; cb += 256) {
            const int c = cb + (lane << 2);
            const float4 xv = *(const float4*)(xsd + c);
            const ushort4 a0 = *(const ushort4*)(A0 + c);
            const ushort4 a1 = *(const ushort4*)(A0 + N + c);
            const ushort4 a2 = *(const ushort4*)(A0 + 2 * N + c);
            const ushort4 a3 = *(const ushort4*)(A0 + 3 * N + c);
            acc0 += bf2f(a0.x)*xv.x + bf2f(a0.y)*xv.y + bf2f(a0.z)*xv.z + bf2f(a0.w)*xv.w;
            acc1 += bf2f(a1.x)*xv.x + bf2f(a1.y)*xv.y + bf2f(a1.z)*xv.z + bf2f(a1.w)*xv.w;
            acc2 += bf2f(a2.x)*xv.x + bf2f(a2.y)*xv.y + bf2f(a2.z)*xv.z + bf2f(a2.w)*xv.w;
            acc3 += bf2f(a3.x)*xv.x + bf2f(a3.y)*xv.y + bf2f(a3.z)*xv.z + bf2f(a3.w)*xv.w;
        }
    }
#pragma unroll
    for (int off = 32; off > 0; off >>= 1) {
        acc0 += __shfl_xor(acc0, off, 64);
        acc1 += __shfl_xor(acc1, off, 64);
        acc2 += __shfl_xor(acc2, off, 64);
        acc3 += __shfl_xor(acc3, off, 64);
    }
    if (lane < 4) {
        float acc = (lane == 0) ? acc0 : (lane == 1) ? acc1 : (lane == 2) ? acc2 : acc3;
        const int idx = head * N + row + lane;
        const float bval = isf32 ? ((const float*)bv)[idx]
                                 : bf2f(((const unsigned short*)bv)[idx]);
        const float y = tanhf(FPL_GAMMA * acc + bval);
        if (FINAL) out[idx] = y;
        else       g_x[1 - src][idx] = y;
    }
}

extern "C" void kernel_launch(void* const* d_in, const int* in_sizes, int n_in,
                              void* d_out, int out_size, void* d_ws, size_t ws_size,
                              hipStream_t stream) {
    (void)d_ws; (void)ws_size; (void)n_in; (void)out_size;
    const void* A = d_in[0];
    const void* b = d_in[1];
    long szA = in_sizes[0], szb = in_sizes[1];
    if (szA < szb) { const void* t = A; A = b; b = t; long s = szA; szA = szb; szb = s; }
    const int HN = (int)szb;
    const int N  = (int)(szA / szb);
    float* out = (float*)d_out;

    // probe zeroes the per-block flags (graph-replay safe) + dtype detect
    fpl_probe<<<dim3(1), dim3(256), 0, stream>>>((const unsigned short*)A);

    bool done = false;
    if (N == COOP_N && HN == COOP_HN) {
        void* args[] = { (void*)&A, (void*)&b, (void*)&out };
        hipError_t rc = hipLaunchCooperativeKernel((const void*)fpl_coop,
                                                   dim3(256), dim3(512),
                                                   args, 0, stream);
        done = (rc == hipSuccess);
    }
    if (!done) {
        fpl_init<<<dim3((HN + 255) / 256), dim3(256), 0, stream>>>(b, HN);
        const int grid = HN >> 4;
        const size_t lds = (size_t)N * sizeof(float);
        int src = 0;
        for (int s = 0; s < FB_STEPS; ++s) {
            fpl_step_raw<false><<<dim3(grid), dim3(256), lds, stream>>>(A, b, src, N, nullptr);
            src ^= 1;
        }
        fpl_step_raw<true><<<dim3(grid), dim3(256), lds, stream>>>(A, b, src, N, out);
    }
}